// Round 6
// baseline (5657.788 us; speedup 1.0000x reference)
//
#include <hip/hip_runtime.h>
#include <hip/hip_bf16.h>

#define N_NODES 25000
#define N_EDGES 400000
#define S 64
#define V 32
#define L2C 16
#define TDIM 64
#define D 336          // S + 6V + 5*L2
#define FILMD 208

#define ES_STR 264     // es row stride in bf16
#define HID_STR 136    // hid row stride in bf16

typedef short bf8 __attribute__((ext_vector_type(8)));
typedef float f4  __attribute__((ext_vector_type(4)));

__device__ __forceinline__ float silu_f(float x) { return x / (1.0f + __expf(-x)); }

__device__ __forceinline__ float wsum64(float x) {
    #pragma unroll
    for (int m = 32; m > 0; m >>= 1) x += __shfl_xor(x, m, 64);
    return x;
}
__device__ __forceinline__ float wsum32(float x) {
    #pragma unroll
    for (int m = 16; m > 0; m >>= 1) x += __shfl_xor(x, m, 32);
    return x;
}
__device__ __forceinline__ float wsum16(float x) {
    #pragma unroll
    for (int m = 8; m > 0; m >>= 1) x += __shfl_xor(x, m, 16);
    return x;
}

// ---------------- weight conversion (bf16, transposed) ----------------
__global__ __launch_bounds__(256) void convert_weights(
    const float* __restrict__ W1, const float* __restrict__ W2,
    __hip_bfloat16* __restrict__ Wb1t, __hip_bfloat16* __restrict__ Wb2t)
{
    const int i = blockIdx.x * 256 + threadIdx.x;
    if (i < 128 * 256) {
        const int n = i >> 8, k = i & 255;
        const float v = (k < 252) ? W1[k * 128 + n] : 0.0f;
        Wb1t[i] = __float2bfloat16(v);
    }
    if (i < 432 * 128) {
        const int n = i >> 7, k = i & 127;
        Wb2t[i] = __float2bfloat16(W2[k * 432 + n]);
    }
}

// ---------------- per-node projections hproj[n][48] = [h0@Wsv | h0@Wsl] ----------------
__global__ __launch_bounds__(256) void hproj_kernel(
    const float* __restrict__ h, const float* __restrict__ Wsv,
    const float* __restrict__ Wsl, float* __restrict__ hproj)
{
    const int idx = blockIdx.x * 256 + threadIdx.x;
    if (idx >= N_NODES * 48) return;
    const int n = idx / 48, o = idx - n * 48;
    const float* hr = h + (size_t)n * D;
    float a = 0.f;
    if (o < 32) {
        #pragma unroll 4
        for (int j = 0; j < 64; j++) a = fmaf(hr[j], Wsv[j * 32 + o], a);
    } else {
        const int c = o - 32;
        #pragma unroll 4
        for (int j = 0; j < 64; j++) a = fmaf(hr[j], Wsl[j * 16 + c], a);
    }
    hproj[idx] = a;
}

// ---------------- counting sort by dst (CSR build) ----------------
__global__ __launch_bounds__(256) void hist_kernel(const int* __restrict__ eidx, int* __restrict__ cnt) {
    const int e = blockIdx.x * 256 + threadIdx.x;
    if (e < N_EDGES) atomicAdd(&cnt[eidx[N_EDGES + e]], 1);
}

__global__ __launch_bounds__(1024) void scan_kernel(const int* __restrict__ cnt, int* __restrict__ offs) {
    __shared__ int part[1024];
    const int t = threadIdx.x;
    const int base = t * 25;               // 1024*25 = 25600 >= 25000
    int s = 0;
    for (int k = 0; k < 25; k++) {
        const int b = base + k;
        s += (b < N_NODES) ? cnt[b] : 0;
    }
    part[t] = s;
    __syncthreads();
    for (int off = 1; off < 1024; off <<= 1) {
        int v = (t >= off) ? part[t - off] : 0;
        __syncthreads();
        part[t] += v;
        __syncthreads();
    }
    int run = (t > 0) ? part[t - 1] : 0;
    for (int k = 0; k < 25; k++) {
        const int b = base + k;
        if (b < N_NODES) { offs[b] = run; run += cnt[b]; }
    }
    if (t == 1023) offs[N_NODES] = part[1023];
}

__global__ __launch_bounds__(256) void scatter_sort_kernel(
    const int* __restrict__ eidx, const int* __restrict__ offs,
    int* __restrict__ cur, int* __restrict__ sorted)
{
    const int e = blockIdx.x * 256 + threadIdx.x;
    if (e < N_EDGES) {
        const int d = eidx[N_EDGES + e];
        const int p = offs[d] + atomicAdd(&cur[d], 1);
        if (p >= 0 && p < N_EDGES) sorted[p] = e;   // guard: never write OOB
    }
}

// ---------------- MLP chunk kernel: 64 sorted edges / block -> w_buf (sorted order) ----------------
__global__ __launch_bounds__(256, 3) void mlp_chunk(
    const float* __restrict__ h, const float* __restrict__ coords,
    const int* __restrict__ eidx, const int* __restrict__ sorted,
    const int* __restrict__ offs, int n_lo, int n_hi,
    const int* __restrict__ etype, const int* __restrict__ ebt,
    const int* __restrict__ econj, const int* __restrict__ ering,
    const int* __restrict__ est, const float* __restrict__ eref,
    const float* __restrict__ t_emb,
    const float* __restrict__ type_emb, const float* __restrict__ bt_emb,
    const float* __restrict__ conj_emb, const float* __restrict__ ring_emb,
    const float* __restrict__ st_emb,
    const float* __restrict__ refW, const float* __restrict__ refb,
    const __hip_bfloat16* __restrict__ Wb1t, const float* __restrict__ b1,
    const __hip_bfloat16* __restrict__ Wb2t, const float* __restrict__ b2,
    __hip_bfloat16* __restrict__ w_buf)
{
    __shared__ __hip_bfloat16 esA[64 * ES_STR];   // 33792 B
    __shared__ __hip_bfloat16 hidA[64 * HID_STR]; // 17408 B   -> 51200 B, 3 blocks/CU

    const int wid = threadIdx.x >> 6;
    const int l   = threadIdx.x & 63;
    const int pbase = offs[n_lo];
    const int pend  = offs[n_hi];
    const int start = pbase + blockIdx.x * 64;
    if (start >= pend) return;

    // ---------------- Stage 1: edge features -> es (bf16) ----------------
    for (int i = 0; i < 16; i++) {
        const int le = wid * 16 + i;
        const int p  = start + le;
        const int pc = (p < pend) ? p : (pend - 1);
        const int e  = __builtin_amdgcn_readfirstlane(sorted[pc]);
        const int src = __builtin_amdgcn_readfirstlane(eidx[e]);
        const int dst = __builtin_amdgcn_readfirstlane(eidx[N_EDGES + e]);
        const float* cs = coords + 3 * src;
        const float* cd = coords + 3 * dst;
        const float dx = cd[0] - cs[0], dy = cd[1] - cs[1], dz = cd[2] - cs[2];
        const float dist = sqrtf(dx * dx + dy * dy + dz * dz + 1e-12f);
        __hip_bfloat16* es = esA + le * ES_STR;
        es[60 + l]  = __float2bfloat16(h[(size_t)src * D + l]);
        es[124 + l] = __float2bfloat16(h[(size_t)dst * D + l]);
        es[188 + l] = __float2bfloat16(t_emb[(size_t)dst * TDIM + l]);
        const int et = etype[e];
        const int bt = ebt[e];
        const int ci = (bt >= 0) ? econj[e] : 2;
        const int ri = (bt >= 0) ? ering[e] : 2;
        const int si = est[e] + 1;
        const float er = eref[e];
        if (l < 16) {
            const float mu = (float)l * (5.0f / 15.0f);
            const float t = (dist - mu) * 3.0f;
            es[l] = __float2bfloat16(__expf(-t * t));
            es[16 + l] = __float2bfloat16(type_emb[et * 16 + l]);
        }
        if (l < 8) {
            es[32 + l] = __float2bfloat16(bt_emb[(bt + 1) * 8 + l]);
            const float ddv = dist - er;
            const float hr = (er > 0.f) ? 1.f : 0.f;
            es[52 + l] = __float2bfloat16(
                fabsf(ddv) * refW[l] + ddv * refW[8 + l] + hr * refW[16 + l] + refb[l]);
        }
        if (l < 4) {
            es[40 + l] = __float2bfloat16(conj_emb[ci * 4 + l]);
            es[44 + l] = __float2bfloat16(ring_emb[ri * 4 + l]);
            es[48 + l] = __float2bfloat16(st_emb[si * 4 + l]);
            es[252 + l] = __float2bfloat16(0.0f);  // K padding
        }
    }
    __syncthreads();

    // ---------------- Stage 2: GEMM1  hid[64x128] = silu(es @ W1 + b1) ----------------
    {
        const int q = l >> 4;
        const int t16 = l & 15;
        f4 acc[4][2];
        #pragma unroll
        for (int mt = 0; mt < 4; mt++)
            #pragma unroll
            for (int nt = 0; nt < 2; nt++) acc[mt][nt] = (f4){0.f, 0.f, 0.f, 0.f};
        const int n0 = wid * 32 + t16;
        #pragma unroll
        for (int kk = 0; kk < 256; kk += 32) {
            const int k0 = kk + q * 8;
            bf8 a[4];
            #pragma unroll
            for (int mt = 0; mt < 4; mt++)
                a[mt] = *(const bf8*)(esA + (mt * 16 + t16) * ES_STR + k0);
            bf8 b[2];
            b[0] = *(const bf8*)(Wb1t + (size_t)n0 * 256 + k0);
            b[1] = *(const bf8*)(Wb1t + (size_t)(n0 + 16) * 256 + k0);
            #pragma unroll
            for (int mt = 0; mt < 4; mt++) {
                acc[mt][0] = __builtin_amdgcn_mfma_f32_16x16x32_bf16(a[mt], b[0], acc[mt][0], 0, 0, 0);
                acc[mt][1] = __builtin_amdgcn_mfma_f32_16x16x32_bf16(a[mt], b[1], acc[mt][1], 0, 0, 0);
            }
        }
        const float bias0 = b1[n0], bias1 = b1[n0 + 16];
        #pragma unroll
        for (int mt = 0; mt < 4; mt++) {
            #pragma unroll
            for (int r = 0; r < 4; r++) {
                const int m = mt * 16 + q * 4 + r;
                hidA[m * HID_STR + n0]      = __float2bfloat16(silu_f(acc[mt][0][r] + bias0));
                hidA[m * HID_STR + n0 + 16] = __float2bfloat16(silu_f(acc[mt][1][r] + bias1));
            }
        }
    }
    __syncthreads();

    // ---------------- Stage 3: GEMM2 -> w_buf rows (sorted-position order) ----------------
    {
        const int q = l >> 4;
        const int t16 = l & 15;
        bf8 a2[4][4];
        #pragma unroll
        for (int ks = 0; ks < 4; ks++) {
            const int k0 = ks * 32 + q * 8;
            #pragma unroll
            for (int mt = 0; mt < 4; mt++)
                a2[mt][ks] = *(const bf8*)(hidA + (mt * 16 + t16) * HID_STR + k0);
        }
        const size_t wb = (size_t)(start - pbase);
        for (int t = wid; t < 27; t += 4) {
            const int n = t * 16 + t16;
            f4 acc[4];
            #pragma unroll
            for (int mt = 0; mt < 4; mt++) acc[mt] = (f4){0.f, 0.f, 0.f, 0.f};
            #pragma unroll
            for (int ks = 0; ks < 4; ks++) {
                const bf8 b = *(const bf8*)(Wb2t + (size_t)n * 128 + ks * 32 + q * 8);
                #pragma unroll
                for (int mt = 0; mt < 4; mt++)
                    acc[mt] = __builtin_amdgcn_mfma_f32_16x16x32_bf16(a2[mt][ks], b, acc[mt], 0, 0, 0);
            }
            const float bias = b2[n];
            #pragma unroll
            for (int mt = 0; mt < 4; mt++) {
                #pragma unroll
                for (int r = 0; r < 4; r++) {
                    const int m = mt * 16 + q * 4 + r;
                    w_buf[(wb + m) * 432 + n] = __float2bfloat16(acc[mt][r] + bias);
                }
            }
        }
    }
}

// ---------------- Gather chunk kernel: one wave per dst node, fused node epilogue ----------------
struct ER {
    float csx, csy, csz;
    float h0, w0, w1, w2;
    // lanes 0..31:
    float a0, a1, a2, b0, b1, b2, pxv;
    float w3, w4, w5, w6, w7, w8;
    // lanes 32..63:
    float c0, c1, c2, c3, c4, pxl;
    float w9, w10, w11;
};

__global__ __launch_bounds__(256, 4) void gather_chunk(
    const float* __restrict__ h, const float* __restrict__ coords,
    const int* __restrict__ eidx, const int* __restrict__ sorted,
    const int* __restrict__ offs, int n_lo, int n_hi,
    const __hip_bfloat16* __restrict__ w_buf,
    const float* __restrict__ hproj, const float* __restrict__ t_emb,
    const float* __restrict__ Wvs, const float* __restrict__ Wls,
    const float* __restrict__ Wlv, const float* __restrict__ Wvl,
    const float* __restrict__ P0, const float* __restrict__ P1o,
    const float* __restrict__ P1e, const float* __restrict__ P2,
    const float* __restrict__ filmW, const float* __restrict__ filmb,
    float* __restrict__ out)
{
    __shared__ float sc[4][256];    // dv32 | ql16 | eci48 | t112 160
    __shared__ float agL[4][344];
    __shared__ float tvL[4][64];

    const int wid = threadIdx.x >> 6;
    const int l   = threadIdx.x & 63;
    const int n   = n_lo + blockIdx.x * 4 + wid;
    if (n >= n_hi) return;

    float* dv   = sc[wid];
    float* ql   = dv + 32;
    float* eci  = ql + 16;
    float* t112 = eci + 48;
    float* ag   = agL[wid];
    float* tv   = tvL[wid];

    const float R2 = 0.7071067811865476f;
    const float R6 = 0.4082482904638631f;

    const float cdx = coords[3 * n], cdy = coords[3 * n + 1], cdz = coords[3 * n + 2];
    const int pbase = offs[n_lo];
    const int pbeg = offs[n], pend = offs[n + 1];
    const int vv = l & 31, cc = l & 15;
    const bool loV = (l < 32);
    const bool hiA = (l >= 32) && !(l & 16);   // lanes 32..47
    const int v0 = (l & 16) ? 16 : 0;          // m2 v-half for lanes 32..63

    float am0 = 0.f;
    float am1[6] = {0.f, 0.f, 0.f, 0.f, 0.f, 0.f};
    float am2[5] = {0.f, 0.f, 0.f, 0.f, 0.f};

    auto loadE = [&](int p) -> ER {
        ER r;
        const int e   = __builtin_amdgcn_readfirstlane(sorted[p]);
        const int src = __builtin_amdgcn_readfirstlane(eidx[e]);
        const float* hr = h + (size_t)src * D;
        r.csx = coords[3 * src]; r.csy = coords[3 * src + 1]; r.csz = coords[3 * src + 2];
        r.h0 = hr[l];
        const __hip_bfloat16* wr = w_buf + (size_t)(p - pbase) * 432;
        r.w0 = __bfloat162float(wr[l]);
        r.w1 = __bfloat162float(wr[64 + l]);
        r.w2 = __bfloat162float(wr[128 + l]);
        if (loV) {
            r.a0 = hr[64 + 3 * vv];  r.a1 = hr[65 + 3 * vv];  r.a2 = hr[66 + 3 * vv];
            r.b0 = hr[160 + 3 * vv]; r.b1 = hr[161 + 3 * vv]; r.b2 = hr[162 + 3 * vv];
            r.pxv = hproj[(size_t)src * 48 + vv];
            r.w3 = __bfloat162float(wr[192 + vv]);
            r.w4 = __bfloat162float(wr[224 + vv]);
            r.w5 = __bfloat162float(wr[256 + vv]);
            r.w6 = __bfloat162float(wr[288 + vv]);
            r.w7 = __bfloat162float(wr[320 + vv]);
            r.w8 = __bfloat162float(wr[352 + vv]);
        } else {
            r.c0 = hr[256 + 5 * cc]; r.c1 = hr[257 + 5 * cc]; r.c2 = hr[258 + 5 * cc];
            r.c3 = hr[259 + 5 * cc]; r.c4 = hr[260 + 5 * cc];
            r.pxl = hproj[(size_t)src * 48 + 32 + cc];
            r.w9  = __bfloat162float(wr[384 + cc]);
            r.w10 = __bfloat162float(wr[400 + cc]);
            r.w11 = __bfloat162float(wr[416 + cc]);
        }
        return r;
    };

    ER nxt = {};
    if (pbeg < pend) nxt = loadE(pbeg);

    for (int p = pbeg; p < pend; p++) {
        const ER cur = nxt;
        if (p + 1 < pend) nxt = loadE(p + 1);

        const float dx = cdx - cur.csx, dy = cdy - cur.csy, dz = cdz - cur.csz;
        const float dist = sqrtf(dx * dx + dy * dy + dz * dz + 1e-12f);
        const float inv = 1.0f / dist;
        const float ux = dx * inv, uy = dy * inv, uz = dz * inv;
        float y2a[5];
        y2a[0] = 2.f * R2 * ux * uy;
        y2a[1] = 2.f * R2 * ux * uz;
        y2a[2] = 2.f * R2 * uy * uz;
        y2a[3] = R2 * (ux * ux - uy * uy);
        y2a[4] = R6 * (ux * ux + uy * uy - 2.f * uz * uz);

        if (loV) {
            dv[l] = cur.a0 * ux + cur.a1 * uy + cur.a2 * uz;
            t112[l * 5 + 0] = R2 * (cur.a0 * uy + cur.a1 * ux);
            t112[l * 5 + 1] = R2 * (cur.a0 * uz + cur.a2 * ux);
            t112[l * 5 + 2] = R2 * (cur.a1 * uz + cur.a2 * uy);
            t112[l * 5 + 3] = R2 * (cur.a0 * ux - cur.a1 * uy);
            t112[l * 5 + 4] = R6 * (cur.a0 * ux + cur.a1 * uy - 2.f * cur.a2 * uz);
        } else if (hiA) {
            ql[cc] = cur.c0 * y2a[0] + cur.c1 * y2a[1] + cur.c2 * y2a[2]
                   + cur.c3 * y2a[3] + cur.c4 * y2a[4];
            eci[cc * 3 + 0] = R2 * (cur.c0 * uy + cur.c1 * uz + cur.c3 * ux) + R6 * cur.c4 * ux;
            eci[cc * 3 + 1] = R2 * (cur.c0 * ux + cur.c2 * uz - cur.c3 * uy) + R6 * cur.c4 * uy;
            eci[cc * 3 + 2] = R2 * (cur.c1 * ux + cur.c2 * uy) - 2.f * R6 * cur.c4 * uz;
        }

        // m0 (all lanes, channel l) — dv/ql written above by this wave (wave-synchronous LDS)
        {
            float t1 = 0.f, t2 = 0.f;
            #pragma unroll
            for (int v = 0; v < 32; v++) t1 = fmaf(dv[v], Wvs[v * 64 + l], t1);
            #pragma unroll
            for (int c = 0; c < 16; c++) t2 = fmaf(ql[c], Wls[c * 64 + l], t2);
            am0 += cur.w0 * cur.h0 + cur.w1 * t1 + cur.w2 * t2;
        }

        if (loV) {
            // m1o / m1e (lanes 0..31, v = l)
            const int v = l;
            const float co0 = cur.b1 * uz - cur.b2 * uy;
            const float co1 = cur.b2 * ux - cur.b0 * uz;
            const float co2 = cur.b0 * uy - cur.b1 * ux;
            const float ce0 = cur.a1 * uz - cur.a2 * uy;
            const float ce1 = cur.a2 * ux - cur.a0 * uz;
            const float ce2 = cur.a0 * uy - cur.a1 * ux;
            float t0 = 0.f, t1 = 0.f, t2 = 0.f;
            #pragma unroll
            for (int c = 0; c < 16; c++) {
                const float wl = Wlv[c * 32 + v];
                t0 = fmaf(eci[c * 3 + 0], wl, t0);
                t1 = fmaf(eci[c * 3 + 1], wl, t1);
                t2 = fmaf(eci[c * 3 + 2], wl, t2);
            }
            am1[0] += cur.w3 * cur.a0 + cur.w4 * cur.pxv * ux + cur.w5 * co0 + cur.w6 * t0;
            am1[1] += cur.w3 * cur.a1 + cur.w4 * cur.pxv * uy + cur.w5 * co1 + cur.w6 * t1;
            am1[2] += cur.w3 * cur.a2 + cur.w4 * cur.pxv * uz + cur.w5 * co2 + cur.w6 * t2;
            am1[3] += cur.w7 * cur.b0 + cur.w8 * ce0;
            am1[4] += cur.w7 * cur.b1 + cur.w8 * ce1;
            am1[5] += cur.w7 * cur.b2 + cur.w8 * ce2;
        } else {
            // m2 (lanes 32..63, channel cc, v-half v0..v0+15)
            float tl0 = 0, tl1 = 0, tl2 = 0, tl3 = 0, tl4 = 0;
            #pragma unroll
            for (int vk = 0; vk < 16; vk++) {
                const int v = v0 + vk;
                const float wv = Wvl[v * 16 + cc];
                tl0 = fmaf(t112[v * 5 + 0], wv, tl0);
                tl1 = fmaf(t112[v * 5 + 1], wv, tl1);
                tl2 = fmaf(t112[v * 5 + 2], wv, tl2);
                tl3 = fmaf(t112[v * 5 + 3], wv, tl3);
                tl4 = fmaf(t112[v * 5 + 4], wv, tl4);
            }
            am2[0] += cur.w10 * tl0;
            am2[1] += cur.w10 * tl1;
            am2[2] += cur.w10 * tl2;
            am2[3] += cur.w10 * tl3;
            am2[4] += cur.w10 * tl4;
            if (hiA) {   // add the non-split terms exactly once
                am2[0] += cur.w9 * cur.c0 + cur.w11 * cur.pxl * y2a[0];
                am2[1] += cur.w9 * cur.c1 + cur.w11 * cur.pxl * y2a[1];
                am2[2] += cur.w9 * cur.c2 + cur.w11 * cur.pxl * y2a[2];
                am2[3] += cur.w9 * cur.c3 + cur.w11 * cur.pxl * y2a[3];
                am2[4] += cur.w9 * cur.c4 + cur.w11 * cur.pxl * y2a[4];
            }
        }
    }

    // combine m2 v-halves (lane 32+c gets lane 48+c's partial and vice versa)
    #pragma unroll
    for (int k = 0; k < 5; k++) am2[k] += __shfl_xor(am2[k], 16, 64);

    // ---------------- stash accumulated messages to LDS (wave-synchronous) ----------------
    ag[l] = am0;
    if (loV) {
        ag[64 + 3 * l + 0] = am1[0];
        ag[64 + 3 * l + 1] = am1[1];
        ag[64 + 3 * l + 2] = am1[2];
        ag[160 + 3 * l + 0] = am1[3];
        ag[160 + 3 * l + 1] = am1[4];
        ag[160 + 3 * l + 2] = am1[5];
    }
    if (hiA) {
        #pragma unroll
        for (int k = 0; k < 5; k++) ag[256 + 5 * cc + k] = am2[k];
    }
    tv[l] = t_emb[(size_t)n * TDIM + l];

    const float* hrow = h + (size_t)n * D;

    const int c2 = 128 + l;
    const int c3 = 192 + (l & 15);
    float f0 = filmb[l], f1 = filmb[64 + l], f2 = filmb[c2], f3 = filmb[c3];
    #pragma unroll 4
    for (int t = 0; t < 64; t++) {
        const float tt = tv[t];
        const float* fr = filmW + t * FILMD;
        f0 = fmaf(tt, fr[l], f0);
        f1 = fmaf(tt, fr[64 + l], f1);
        f2 = fmaf(tt, fr[c2], f2);
        f3 = fmaf(tt, fr[c3], f3);
    }

    {
        float a0 = 0.f;
        #pragma unroll 4
        for (int j = 0; j < 64; j++) a0 = fmaf(ag[j], P0[j * 64 + l], a0);
        a0 = silu_f(a0);
        const float hn0 = hrow[l] + a0;
        const float mu = wsum64(hn0) * (1.0f / 64.0f);
        const float d0 = hn0 - mu;
        const float var = wsum64(d0 * d0) * (1.0f / 64.0f);
        out[(size_t)n * D + l] = d0 * rsqrtf(var + 1e-6f) * (1.f + f0) + f1;
    }

    {
        const int v = l & 31;
        const bool iso = (l < 32);
        const float* Pm = iso ? P1o : P1e;
        const int base = iso ? 64 : 160;
        float a0 = 0.f, a1 = 0.f, a2 = 0.f;
        #pragma unroll 4
        for (int u = 0; u < 32; u++) {
            const float p = Pm[u * 32 + v];
            a0 = fmaf(ag[base + 3 * u + 0], p, a0);
            a1 = fmaf(ag[base + 3 * u + 1], p, a1);
            a2 = fmaf(ag[base + 3 * u + 2], p, a2);
        }
        const float x0 = hrow[base + 3 * v + 0] + a0;
        const float x1 = hrow[base + 3 * v + 1] + a1;
        const float x2 = hrow[base + 3 * v + 2] + a2;
        const float ssq = x0 * x0 + x1 * x1 + x2 * x2;
        const float s = wsum32(ssq);
        const float rinv = rsqrtf(s * (1.f / 32.f) + 1e-6f);
        const float scv = (1.f + f2) * rinv;
        out[(size_t)n * D + base + 3 * v + 0] = x0 * scv;
        out[(size_t)n * D + base + 3 * v + 1] = x1 * scv;
        out[(size_t)n * D + base + 3 * v + 2] = x2 * scv;
    }

    {
        const int c = l & 15;
        float xk[5];
        float ssq = 0.f;
        #pragma unroll
        for (int k = 0; k < 5; k++) {
            float a = 0.f;
            #pragma unroll
            for (int u = 0; u < 16; u++) a = fmaf(ag[256 + 5 * u + k], P2[u * 16 + c], a);
            const float x = hrow[256 + 5 * c + k] + a;
            xk[k] = x;
            ssq += x * x;
        }
        const float s = wsum16(ssq);
        const float rinv = rsqrtf(s * (1.f / 16.f) + 1e-6f);
        const float scv = (1.f + f3) * rinv;
        if (l < 16) {
            #pragma unroll
            for (int k = 0; k < 5; k++) out[(size_t)n * D + 256 + 5 * c + k] = xk[k] * scv;
        }
    }
}

extern "C" void kernel_launch(void* const* d_in, const int* in_sizes, int n_in,
                              void* d_out, int out_size, void* d_ws, size_t ws_size,
                              hipStream_t stream)
{
    const float* h        = (const float*)d_in[0];
    const float* coords   = (const float*)d_in[1];
    const int*   eidx     = (const int*)d_in[2];
    const int*   etype    = (const int*)d_in[3];
    const int*   ebt      = (const int*)d_in[4];
    const int*   econj    = (const int*)d_in[5];
    const int*   ering    = (const int*)d_in[6];
    const int*   est      = (const int*)d_in[7];
    const float* eref     = (const float*)d_in[8];
    const float* t_emb    = (const float*)d_in[9];
    const float* type_emb = (const float*)d_in[10];
    const float* bt_emb   = (const float*)d_in[11];
    const float* conj_emb = (const float*)d_in[12];
    const float* ring_emb = (const float*)d_in[13];
    const float* st_emb   = (const float*)d_in[14];
    const float* refW     = (const float*)d_in[15];
    const float* refb     = (const float*)d_in[16];
    const float* W1       = (const float*)d_in[17];
    const float* b1       = (const float*)d_in[18];
    const float* W2       = (const float*)d_in[19];
    const float* b2       = (const float*)d_in[20];
    const float* Wvs      = (const float*)d_in[21];
    const float* Wls      = (const float*)d_in[22];
    const float* Wsv      = (const float*)d_in[23];
    const float* Wlv      = (const float*)d_in[24];
    const float* Wvl      = (const float*)d_in[25];
    const float* Wsl      = (const float*)d_in[26];
    const float* P0       = (const float*)d_in[27];
    const float* P1o      = (const float*)d_in[28];
    const float* P1e      = (const float*)d_in[29];
    const float* P2       = (const float*)d_in[30];
    const float* filmW    = (const float*)d_in[31];
    const float* filmb    = (const float*)d_in[32];

    float* out = (float*)d_out;

    // ---------------- workspace layout ----------------
    // All int arrays CONTIGUOUS (no alignment padding between cnt and cur!) so one
    // memset of 2*N_NODES ints covers cnt+cur exactly. (Round-5 crash: padding
    // between cnt and cur left cur's tail 0xAA-poisoned -> scatter wrote OOB.)
    char* base = (char*)d_ws;
    size_t off = 0;
    auto alloc = [&](size_t bytes, size_t align) -> char* {
        off = (off + align - 1) / align * align;
        char* p = base + off;
        off += bytes;
        return p;
    };
    int* cnt = (int*)alloc((size_t)(2 * N_NODES + N_NODES + 1 + N_EDGES) * sizeof(int), 256);
    int* cur    = cnt + N_NODES;
    int* offs   = cur + N_NODES;
    int* sorted = offs + N_NODES + 1;
    float* hproj = (float*)alloc((size_t)N_NODES * 48 * sizeof(float), 256);
    __hip_bfloat16* Wb1t = (__hip_bfloat16*)alloc(128 * 256 * 2, 256);
    __hip_bfloat16* Wb2t = (__hip_bfloat16*)alloc(432 * 128 * 2, 256);
    off = (off + 255) / 256 * 256;
    __hip_bfloat16* w_buf = (__hip_bfloat16*)(base + off);
    size_t rem = (ws_size > off) ? (ws_size - off) : 0;

    // w_buf capacity (edges) and chunking
    long cap_edges = (long)(rem / (432 * 2));
    int EBLK = (int)(cap_edges / 64);                 // blocks per mlp_chunk launch
    if (EBLK > (N_EDGES + 63) / 64) EBLK = (N_EDGES + 63) / 64;
    if (EBLK < 1) EBLK = 1;
    int NCH, nchunks;
    if ((long)EBLK * 64 >= N_EDGES) {
        NCH = N_NODES; nchunks = 1;
    } else {
        NCH = (int)((long)EBLK * 64 / 21);            // mean degree 16, +31% margin (>5 sigma)
        if (NCH < 1) NCH = 1;
        nchunks = (N_NODES + NCH - 1) / NCH;
    }

    hipMemsetAsync(cnt, 0, 2 * N_NODES * sizeof(int), stream);

    convert_weights<<<(432 * 128 + 255) / 256, 256, 0, stream>>>(W1, W2, Wb1t, Wb2t);
    hproj_kernel<<<(N_NODES * 48 + 255) / 256, 256, 0, stream>>>(h, Wsv, Wsl, hproj);
    hist_kernel<<<(N_EDGES + 255) / 256, 256, 0, stream>>>(eidx, cnt);
    scan_kernel<<<1, 1024, 0, stream>>>(cnt, offs);
    scatter_sort_kernel<<<(N_EDGES + 255) / 256, 256, 0, stream>>>(eidx, offs, cur, sorted);

    for (int k = 0; k < nchunks; k++) {
        const int n_lo = k * NCH;
        int n_hi = n_lo + NCH;
        if (n_hi > N_NODES) n_hi = N_NODES;

        mlp_chunk<<<EBLK, 256, 0, stream>>>(
            h, coords, eidx, sorted, offs, n_lo, n_hi,
            etype, ebt, econj, ering, est, eref, t_emb,
            type_emb, bt_emb, conj_emb, ring_emb, st_emb, refW, refb,
            Wb1t, b1, Wb2t, b2, w_buf);

        const int nb = (n_hi - n_lo + 3) / 4;
        gather_chunk<<<nb, 256, 0, stream>>>(
            h, coords, eidx, sorted, offs, n_lo, n_hi, w_buf, hproj, t_emb,
            Wvs, Wls, Wlv, Wvl, P0, P1o, P1e, P2, filmW, filmb, out);
    }
}

// Round 7
// 1884.665 us; speedup vs baseline: 3.0020x; 3.0020x over previous
//
#include <hip/hip_runtime.h>
#include <hip/hip_bf16.h>

#define N_NODES 25000
#define N_EDGES 400000
#define S 64
#define V 32
#define L2C 16
#define TDIM 64
#define D 336          // S + 6V + 5*L2
#define FILMD 208

#define ES_STR 264     // es row stride in bf16
#define HID_STR 136    // hid row stride in bf16

typedef short bf8 __attribute__((ext_vector_type(8)));
typedef float f4  __attribute__((ext_vector_type(4)));

__device__ __forceinline__ float silu_f(float x) { return x / (1.0f + __expf(-x)); }

__device__ __forceinline__ float wsum64(float x) {
    #pragma unroll
    for (int m = 32; m > 0; m >>= 1) x += __shfl_xor(x, m, 64);
    return x;
}
__device__ __forceinline__ float wsum32(float x) {
    #pragma unroll
    for (int m = 16; m > 0; m >>= 1) x += __shfl_xor(x, m, 32);
    return x;
}
__device__ __forceinline__ float wsum16(float x) {
    #pragma unroll
    for (int m = 8; m > 0; m >>= 1) x += __shfl_xor(x, m, 16);
    return x;
}

// ---------------- weight conversion (bf16, transposed) ----------------
__global__ __launch_bounds__(256) void convert_weights(
    const float* __restrict__ W1, const float* __restrict__ W2,
    __hip_bfloat16* __restrict__ Wb1t, __hip_bfloat16* __restrict__ Wb2t)
{
    const int i = blockIdx.x * 256 + threadIdx.x;
    if (i < 128 * 256) {
        const int n = i >> 8, k = i & 255;
        const float v = (k < 252) ? W1[k * 128 + n] : 0.0f;
        Wb1t[i] = __float2bfloat16(v);
    }
    if (i < 432 * 128) {
        const int n = i >> 7, k = i & 127;
        Wb2t[i] = __float2bfloat16(W2[k * 432 + n]);
    }
}

// ---------------- per-node projections hproj[n][48] = [h0@Wsv | h0@Wsl] ----------------
__global__ __launch_bounds__(256) void hproj_kernel(
    const float* __restrict__ h, const float* __restrict__ Wsv,
    const float* __restrict__ Wsl, float* __restrict__ hproj)
{
    const int idx = blockIdx.x * 256 + threadIdx.x;
    if (idx >= N_NODES * 48) return;
    const int n = idx / 48, o = idx - n * 48;
    const float* hr = h + (size_t)n * D;
    float a = 0.f;
    if (o < 32) {
        #pragma unroll 4
        for (int j = 0; j < 64; j++) a = fmaf(hr[j], Wsv[j * 32 + o], a);
    } else {
        const int c = o - 32;
        #pragma unroll 4
        for (int j = 0; j < 64; j++) a = fmaf(hr[j], Wsl[j * 16 + c], a);
    }
    hproj[idx] = a;
}

// ---------------- counting sort by dst (CSR build) ----------------
__global__ __launch_bounds__(256) void hist_kernel(const int* __restrict__ eidx, int* __restrict__ cnt) {
    const int e = blockIdx.x * 256 + threadIdx.x;
    if (e < N_EDGES) atomicAdd(&cnt[eidx[N_EDGES + e]], 1);
}

__global__ __launch_bounds__(1024) void scan_kernel(const int* __restrict__ cnt, int* __restrict__ offs) {
    __shared__ int part[1024];
    const int t = threadIdx.x;
    const int base = t * 25;               // 1024*25 = 25600 >= 25000
    int s = 0;
    for (int k = 0; k < 25; k++) {
        const int b = base + k;
        s += (b < N_NODES) ? cnt[b] : 0;
    }
    part[t] = s;
    __syncthreads();
    for (int off = 1; off < 1024; off <<= 1) {
        int v = (t >= off) ? part[t - off] : 0;
        __syncthreads();
        part[t] += v;
        __syncthreads();
    }
    int run = (t > 0) ? part[t - 1] : 0;
    for (int k = 0; k < 25; k++) {
        const int b = base + k;
        if (b < N_NODES) { offs[b] = run; run += cnt[b]; }
    }
    if (t == 1023) offs[N_NODES] = part[1023];
}

__global__ __launch_bounds__(256) void scatter_sort_kernel(
    const int* __restrict__ eidx, const int* __restrict__ offs,
    int* __restrict__ cur, int* __restrict__ sorted)
{
    const int e = blockIdx.x * 256 + threadIdx.x;
    if (e < N_EDGES) {
        const int d = eidx[N_EDGES + e];
        const int p = offs[d] + atomicAdd(&cur[d], 1);
        if (p >= 0 && p < N_EDGES) sorted[p] = e;   // guard: never write OOB
    }
}

// ---------------- MLP chunk kernel: 64 sorted edges / block -> w_buf (sorted order) ----------------
__global__ __launch_bounds__(256, 3) void mlp_chunk(
    const float* __restrict__ h, const float* __restrict__ coords,
    const int* __restrict__ eidx, const int* __restrict__ sorted,
    const int* __restrict__ offs, int n_lo, int n_hi,
    const int* __restrict__ etype, const int* __restrict__ ebt,
    const int* __restrict__ econj, const int* __restrict__ ering,
    const int* __restrict__ est, const float* __restrict__ eref,
    const float* __restrict__ t_emb,
    const float* __restrict__ type_emb, const float* __restrict__ bt_emb,
    const float* __restrict__ conj_emb, const float* __restrict__ ring_emb,
    const float* __restrict__ st_emb,
    const float* __restrict__ refW, const float* __restrict__ refb,
    const __hip_bfloat16* __restrict__ Wb1t, const float* __restrict__ b1,
    const __hip_bfloat16* __restrict__ Wb2t, const float* __restrict__ b2,
    __hip_bfloat16* __restrict__ w_buf)
{
    __shared__ __hip_bfloat16 esA[64 * ES_STR];   // 33792 B
    __shared__ __hip_bfloat16 hidA[64 * HID_STR]; // 17408 B   -> 51200 B, 3 blocks/CU

    const int wid = threadIdx.x >> 6;
    const int l   = threadIdx.x & 63;
    const int pbase = offs[n_lo];
    const int pend  = offs[n_hi];
    const int start = pbase + blockIdx.x * 64;
    if (start >= pend) return;

    // ---------------- Stage 1: edge features -> es (bf16) ----------------
    for (int i = 0; i < 16; i++) {
        const int le = wid * 16 + i;
        const int p  = start + le;
        const int pc = (p < pend) ? p : (pend - 1);
        const int e  = __builtin_amdgcn_readfirstlane(sorted[pc]);
        const int src = __builtin_amdgcn_readfirstlane(eidx[e]);
        const int dst = __builtin_amdgcn_readfirstlane(eidx[N_EDGES + e]);
        const float* cs = coords + 3 * src;
        const float* cd = coords + 3 * dst;
        const float dx = cd[0] - cs[0], dy = cd[1] - cs[1], dz = cd[2] - cs[2];
        const float dist = sqrtf(dx * dx + dy * dy + dz * dz + 1e-12f);
        __hip_bfloat16* es = esA + le * ES_STR;
        es[60 + l]  = __float2bfloat16(h[(size_t)src * D + l]);
        es[124 + l] = __float2bfloat16(h[(size_t)dst * D + l]);
        es[188 + l] = __float2bfloat16(t_emb[(size_t)dst * TDIM + l]);
        const int et = etype[e];
        const int bt = ebt[e];
        const int ci = (bt >= 0) ? econj[e] : 2;
        const int ri = (bt >= 0) ? ering[e] : 2;
        const int si = est[e] + 1;
        const float er = eref[e];
        if (l < 16) {
            const float mu = (float)l * (5.0f / 15.0f);
            const float t = (dist - mu) * 3.0f;
            es[l] = __float2bfloat16(__expf(-t * t));
            es[16 + l] = __float2bfloat16(type_emb[et * 16 + l]);
        }
        if (l < 8) {
            es[32 + l] = __float2bfloat16(bt_emb[(bt + 1) * 8 + l]);
            const float ddv = dist - er;
            const float hr = (er > 0.f) ? 1.f : 0.f;
            es[52 + l] = __float2bfloat16(
                fabsf(ddv) * refW[l] + ddv * refW[8 + l] + hr * refW[16 + l] + refb[l]);
        }
        if (l < 4) {
            es[40 + l] = __float2bfloat16(conj_emb[ci * 4 + l]);
            es[44 + l] = __float2bfloat16(ring_emb[ri * 4 + l]);
            es[48 + l] = __float2bfloat16(st_emb[si * 4 + l]);
            es[252 + l] = __float2bfloat16(0.0f);  // K padding
        }
    }
    __syncthreads();

    // ---------------- Stage 2: GEMM1  hid[64x128] = silu(es @ W1 + b1) ----------------
    {
        const int q = l >> 4;
        const int t16 = l & 15;
        f4 acc[4][2];
        #pragma unroll
        for (int mt = 0; mt < 4; mt++)
            #pragma unroll
            for (int nt = 0; nt < 2; nt++) acc[mt][nt] = (f4){0.f, 0.f, 0.f, 0.f};
        const int n0 = wid * 32 + t16;
        #pragma unroll
        for (int kk = 0; kk < 256; kk += 32) {
            const int k0 = kk + q * 8;
            bf8 a[4];
            #pragma unroll
            for (int mt = 0; mt < 4; mt++)
                a[mt] = *(const bf8*)(esA + (mt * 16 + t16) * ES_STR + k0);
            bf8 b[2];
            b[0] = *(const bf8*)(Wb1t + (size_t)n0 * 256 + k0);
            b[1] = *(const bf8*)(Wb1t + (size_t)(n0 + 16) * 256 + k0);
            #pragma unroll
            for (int mt = 0; mt < 4; mt++) {
                acc[mt][0] = __builtin_amdgcn_mfma_f32_16x16x32_bf16(a[mt], b[0], acc[mt][0], 0, 0, 0);
                acc[mt][1] = __builtin_amdgcn_mfma_f32_16x16x32_bf16(a[mt], b[1], acc[mt][1], 0, 0, 0);
            }
        }
        const float bias0 = b1[n0], bias1 = b1[n0 + 16];
        #pragma unroll
        for (int mt = 0; mt < 4; mt++) {
            #pragma unroll
            for (int r = 0; r < 4; r++) {
                const int m = mt * 16 + q * 4 + r;
                hidA[m * HID_STR + n0]      = __float2bfloat16(silu_f(acc[mt][0][r] + bias0));
                hidA[m * HID_STR + n0 + 16] = __float2bfloat16(silu_f(acc[mt][1][r] + bias1));
            }
        }
    }
    __syncthreads();

    // ---------------- Stage 3: GEMM2 -> w_buf rows (sorted-position order) ----------------
    {
        const int q = l >> 4;
        const int t16 = l & 15;
        bf8 a2[4][4];
        #pragma unroll
        for (int ks = 0; ks < 4; ks++) {
            const int k0 = ks * 32 + q * 8;
            #pragma unroll
            for (int mt = 0; mt < 4; mt++)
                a2[mt][ks] = *(const bf8*)(hidA + (mt * 16 + t16) * HID_STR + k0);
        }
        const size_t wb = (size_t)(start - pbase);
        for (int t = wid; t < 27; t += 4) {
            const int n = t * 16 + t16;
            f4 acc[4];
            #pragma unroll
            for (int mt = 0; mt < 4; mt++) acc[mt] = (f4){0.f, 0.f, 0.f, 0.f};
            #pragma unroll
            for (int ks = 0; ks < 4; ks++) {
                const bf8 b = *(const bf8*)(Wb2t + (size_t)n * 128 + ks * 32 + q * 8);
                #pragma unroll
                for (int mt = 0; mt < 4; mt++)
                    acc[mt] = __builtin_amdgcn_mfma_f32_16x16x32_bf16(a2[mt][ks], b, acc[mt], 0, 0, 0);
            }
            const float bias = b2[n];
            #pragma unroll
            for (int mt = 0; mt < 4; mt++) {
                #pragma unroll
                for (int r = 0; r < 4; r++) {
                    const int m = mt * 16 + q * 4 + r;
                    w_buf[(wb + m) * 432 + n] = __float2bfloat16(acc[mt][r] + bias);
                }
            }
        }
    }
}

// ---------------- Gather chunk kernel: one wave per dst node, fused node epilogue ----------------
// Round-7 note: round-6's ER-struct prefetch spilled to scratch (VGPR capped 64,
// WRITE_SIZE 2.4 GB/dispatch of spill traffic -> HBM-bound at 2.9 ms). Direct
// in-loop loads + scalar-only index prefetch + (256,2) bounds keep state in VGPRs.
__global__ __launch_bounds__(256, 2) void gather_chunk(
    const float* __restrict__ h, const float* __restrict__ coords,
    const int* __restrict__ eidx, const int* __restrict__ sorted,
    const int* __restrict__ offs, int n_lo, int n_hi,
    const __hip_bfloat16* __restrict__ w_buf,
    const float* __restrict__ hproj, const float* __restrict__ t_emb,
    const float* __restrict__ Wvs, const float* __restrict__ Wls,
    const float* __restrict__ Wlv, const float* __restrict__ Wvl,
    const float* __restrict__ P0, const float* __restrict__ P1o,
    const float* __restrict__ P1e, const float* __restrict__ P2,
    const float* __restrict__ filmW, const float* __restrict__ filmb,
    float* __restrict__ out)
{
    __shared__ float sc[4][256];    // dv32 | ql16 | eci48 | t112 160
    __shared__ float agL[4][344];
    __shared__ float tvL[4][64];

    const int wid = threadIdx.x >> 6;
    const int l   = threadIdx.x & 63;
    const int n   = n_lo + blockIdx.x * 4 + wid;
    if (n >= n_hi) return;

    float* dv   = sc[wid];
    float* ql   = dv + 32;
    float* eci  = ql + 16;
    float* t112 = eci + 48;
    float* ag   = agL[wid];
    float* tv   = tvL[wid];

    const float R2 = 0.7071067811865476f;
    const float R6 = 0.4082482904638631f;

    const float cdx = coords[3 * n], cdy = coords[3 * n + 1], cdz = coords[3 * n + 2];
    const int pbase = offs[n_lo];
    const int pbeg = offs[n], pend = offs[n + 1];
    const int vv = l & 31, cc = l & 15;
    const bool loV = (l < 32);
    const bool hiA = (l >= 32) && !(l & 16);   // lanes 32..47
    const int v0 = (l & 16) ? 16 : 0;          // m2 v-half for lanes 32..63

    float am0 = 0.f;
    float am1[6] = {0.f, 0.f, 0.f, 0.f, 0.f, 0.f};
    float am2[5] = {0.f, 0.f, 0.f, 0.f, 0.f};

    // scalar index prefetch only (2 SGPRs of state)
    int nx_src = 0;
    if (pbeg < pend) {
        const int e0 = __builtin_amdgcn_readfirstlane(sorted[pbeg]);
        nx_src = __builtin_amdgcn_readfirstlane(eidx[e0]);
    }

    for (int p = pbeg; p < pend; p++) {
        const int src = nx_src;
        if (p + 1 < pend) {
            const int e1 = __builtin_amdgcn_readfirstlane(sorted[p + 1]);
            nx_src = __builtin_amdgcn_readfirstlane(eidx[e1]);
        }

        // ---- issue all loads for this edge up front ----
        const float* hr = h + (size_t)src * D;
        const __hip_bfloat16* wr = w_buf + (size_t)(p - pbase) * 432;
        const float csx = coords[3 * src], csy = coords[3 * src + 1], csz = coords[3 * src + 2];
        const float h0 = hr[l];
        const float w0 = __bfloat162float(wr[l]);
        const float w1 = __bfloat162float(wr[64 + l]);
        const float w2 = __bfloat162float(wr[128 + l]);
        float a0, a1, a2, b0, b1, b2, pxv, w3, w4, w5, w6, w7, w8;
        float c0, c1, c2, c3, c4, pxl, w9, w10, w11;
        if (loV) {
            a0 = hr[64 + 3 * vv];  a1 = hr[65 + 3 * vv];  a2 = hr[66 + 3 * vv];
            b0 = hr[160 + 3 * vv]; b1 = hr[161 + 3 * vv]; b2 = hr[162 + 3 * vv];
            pxv = hproj[(size_t)src * 48 + vv];
            w3 = __bfloat162float(wr[192 + vv]);
            w4 = __bfloat162float(wr[224 + vv]);
            w5 = __bfloat162float(wr[256 + vv]);
            w6 = __bfloat162float(wr[288 + vv]);
            w7 = __bfloat162float(wr[320 + vv]);
            w8 = __bfloat162float(wr[352 + vv]);
            c0 = c1 = c2 = c3 = c4 = pxl = w9 = w10 = w11 = 0.f;
        } else {
            c0 = hr[256 + 5 * cc]; c1 = hr[257 + 5 * cc]; c2 = hr[258 + 5 * cc];
            c3 = hr[259 + 5 * cc]; c4 = hr[260 + 5 * cc];
            pxl = hproj[(size_t)src * 48 + 32 + cc];
            w9  = __bfloat162float(wr[384 + cc]);
            w10 = __bfloat162float(wr[400 + cc]);
            w11 = __bfloat162float(wr[416 + cc]);
            a0 = a1 = a2 = b0 = b1 = b2 = pxv = w3 = w4 = w5 = w6 = w7 = w8 = 0.f;
        }

        // ---- geometry ----
        const float dx = cdx - csx, dy = cdy - csy, dz = cdz - csz;
        const float dist = sqrtf(dx * dx + dy * dy + dz * dz + 1e-12f);
        const float inv = 1.0f / dist;
        const float ux = dx * inv, uy = dy * inv, uz = dz * inv;
        float y2a[5];
        y2a[0] = 2.f * R2 * ux * uy;
        y2a[1] = 2.f * R2 * ux * uz;
        y2a[2] = 2.f * R2 * uy * uz;
        y2a[3] = R2 * (ux * ux - uy * uy);
        y2a[4] = R6 * (ux * ux + uy * uy - 2.f * uz * uz);

        if (loV) {
            dv[l] = a0 * ux + a1 * uy + a2 * uz;
            t112[l * 5 + 0] = R2 * (a0 * uy + a1 * ux);
            t112[l * 5 + 1] = R2 * (a0 * uz + a2 * ux);
            t112[l * 5 + 2] = R2 * (a1 * uz + a2 * uy);
            t112[l * 5 + 3] = R2 * (a0 * ux - a1 * uy);
            t112[l * 5 + 4] = R6 * (a0 * ux + a1 * uy - 2.f * a2 * uz);
        } else if (hiA) {
            ql[cc] = c0 * y2a[0] + c1 * y2a[1] + c2 * y2a[2] + c3 * y2a[3] + c4 * y2a[4];
            eci[cc * 3 + 0] = R2 * (c0 * uy + c1 * uz + c3 * ux) + R6 * c4 * ux;
            eci[cc * 3 + 1] = R2 * (c0 * ux + c2 * uz - c3 * uy) + R6 * c4 * uy;
            eci[cc * 3 + 2] = R2 * (c1 * ux + c2 * uy) - 2.f * R6 * c4 * uz;
        }

        // m0 (all lanes, channel l)
        {
            float t1 = 0.f, t2 = 0.f;
            #pragma unroll
            for (int v = 0; v < 32; v++) t1 = fmaf(dv[v], Wvs[v * 64 + l], t1);
            #pragma unroll
            for (int c = 0; c < 16; c++) t2 = fmaf(ql[c], Wls[c * 64 + l], t2);
            am0 += w0 * h0 + w1 * t1 + w2 * t2;
        }

        if (loV) {
            // m1o / m1e (lanes 0..31, v = l)
            const int v = l;
            const float co0 = b1 * uz - b2 * uy;
            const float co1 = b2 * ux - b0 * uz;
            const float co2 = b0 * uy - b1 * ux;
            const float ce0 = a1 * uz - a2 * uy;
            const float ce1 = a2 * ux - a0 * uz;
            const float ce2 = a0 * uy - a1 * ux;
            float t0 = 0.f, t1 = 0.f, t2 = 0.f;
            #pragma unroll
            for (int c = 0; c < 16; c++) {
                const float wl = Wlv[c * 32 + v];
                t0 = fmaf(eci[c * 3 + 0], wl, t0);
                t1 = fmaf(eci[c * 3 + 1], wl, t1);
                t2 = fmaf(eci[c * 3 + 2], wl, t2);
            }
            am1[0] += w3 * a0 + w4 * pxv * ux + w5 * co0 + w6 * t0;
            am1[1] += w3 * a1 + w4 * pxv * uy + w5 * co1 + w6 * t1;
            am1[2] += w3 * a2 + w4 * pxv * uz + w5 * co2 + w6 * t2;
            am1[3] += w7 * b0 + w8 * ce0;
            am1[4] += w7 * b1 + w8 * ce1;
            am1[5] += w7 * b2 + w8 * ce2;
        } else {
            // m2 (lanes 32..63, channel cc, v-half v0..v0+15)
            float tl0 = 0, tl1 = 0, tl2 = 0, tl3 = 0, tl4 = 0;
            #pragma unroll
            for (int vk = 0; vk < 16; vk++) {
                const int v = v0 + vk;
                const float wv = Wvl[v * 16 + cc];
                tl0 = fmaf(t112[v * 5 + 0], wv, tl0);
                tl1 = fmaf(t112[v * 5 + 1], wv, tl1);
                tl2 = fmaf(t112[v * 5 + 2], wv, tl2);
                tl3 = fmaf(t112[v * 5 + 3], wv, tl3);
                tl4 = fmaf(t112[v * 5 + 4], wv, tl4);
            }
            am2[0] += w10 * tl0;
            am2[1] += w10 * tl1;
            am2[2] += w10 * tl2;
            am2[3] += w10 * tl3;
            am2[4] += w10 * tl4;
            if (hiA) {   // add the non-split terms exactly once
                am2[0] += w9 * c0 + w11 * pxl * y2a[0];
                am2[1] += w9 * c1 + w11 * pxl * y2a[1];
                am2[2] += w9 * c2 + w11 * pxl * y2a[2];
                am2[3] += w9 * c3 + w11 * pxl * y2a[3];
                am2[4] += w9 * c4 + w11 * pxl * y2a[4];
            }
        }
    }

    // combine m2 v-halves (lane 32+c gets lane 48+c's partial and vice versa)
    #pragma unroll
    for (int k = 0; k < 5; k++) am2[k] += __shfl_xor(am2[k], 16, 64);

    // ---------------- stash accumulated messages to LDS (wave-synchronous) ----------------
    ag[l] = am0;
    if (loV) {
        ag[64 + 3 * l + 0] = am1[0];
        ag[64 + 3 * l + 1] = am1[1];
        ag[64 + 3 * l + 2] = am1[2];
        ag[160 + 3 * l + 0] = am1[3];
        ag[160 + 3 * l + 1] = am1[4];
        ag[160 + 3 * l + 2] = am1[5];
    }
    if (hiA) {
        #pragma unroll
        for (int k = 0; k < 5; k++) ag[256 + 5 * cc + k] = am2[k];
    }
    tv[l] = t_emb[(size_t)n * TDIM + l];

    const float* hrow = h + (size_t)n * D;

    const int c2 = 128 + l;
    const int c3 = 192 + (l & 15);
    float f0 = filmb[l], f1 = filmb[64 + l], f2 = filmb[c2], f3 = filmb[c3];
    #pragma unroll 4
    for (int t = 0; t < 64; t++) {
        const float tt = tv[t];
        const float* fr = filmW + t * FILMD;
        f0 = fmaf(tt, fr[l], f0);
        f1 = fmaf(tt, fr[64 + l], f1);
        f2 = fmaf(tt, fr[c2], f2);
        f3 = fmaf(tt, fr[c3], f3);
    }

    {
        float a0 = 0.f;
        #pragma unroll 4
        for (int j = 0; j < 64; j++) a0 = fmaf(ag[j], P0[j * 64 + l], a0);
        a0 = silu_f(a0);
        const float hn0 = hrow[l] + a0;
        const float mu = wsum64(hn0) * (1.0f / 64.0f);
        const float d0 = hn0 - mu;
        const float var = wsum64(d0 * d0) * (1.0f / 64.0f);
        out[(size_t)n * D + l] = d0 * rsqrtf(var + 1e-6f) * (1.f + f0) + f1;
    }

    {
        const int v = l & 31;
        const bool iso = (l < 32);
        const float* Pm = iso ? P1o : P1e;
        const int base = iso ? 64 : 160;
        float a0 = 0.f, a1 = 0.f, a2 = 0.f;
        #pragma unroll 4
        for (int u = 0; u < 32; u++) {
            const float p = Pm[u * 32 + v];
            a0 = fmaf(ag[base + 3 * u + 0], p, a0);
            a1 = fmaf(ag[base + 3 * u + 1], p, a1);
            a2 = fmaf(ag[base + 3 * u + 2], p, a2);
        }
        const float x0 = hrow[base + 3 * v + 0] + a0;
        const float x1 = hrow[base + 3 * v + 1] + a1;
        const float x2 = hrow[base + 3 * v + 2] + a2;
        const float ssq = x0 * x0 + x1 * x1 + x2 * x2;
        const float s = wsum32(ssq);
        const float rinv = rsqrtf(s * (1.f / 32.f) + 1e-6f);
        const float scv = (1.f + f2) * rinv;
        out[(size_t)n * D + base + 3 * v + 0] = x0 * scv;
        out[(size_t)n * D + base + 3 * v + 1] = x1 * scv;
        out[(size_t)n * D + base + 3 * v + 2] = x2 * scv;
    }

    {
        const int c = l & 15;
        float xk[5];
        float ssq = 0.f;
        #pragma unroll
        for (int k = 0; k < 5; k++) {
            float a = 0.f;
            #pragma unroll
            for (int u = 0; u < 16; u++) a = fmaf(ag[256 + 5 * u + k], P2[u * 16 + c], a);
            const float x = hrow[256 + 5 * c + k] + a;
            xk[k] = x;
            ssq += x * x;
        }
        const float s = wsum16(ssq);
        const float rinv = rsqrtf(s * (1.f / 16.f) + 1e-6f);
        const float scv = (1.f + f3) * rinv;
        if (l < 16) {
            #pragma unroll
            for (int k = 0; k < 5; k++) out[(size_t)n * D + 256 + 5 * c + k] = xk[k] * scv;
        }
    }
}

extern "C" void kernel_launch(void* const* d_in, const int* in_sizes, int n_in,
                              void* d_out, int out_size, void* d_ws, size_t ws_size,
                              hipStream_t stream)
{
    const float* h        = (const float*)d_in[0];
    const float* coords   = (const float*)d_in[1];
    const int*   eidx     = (const int*)d_in[2];
    const int*   etype    = (const int*)d_in[3];
    const int*   ebt      = (const int*)d_in[4];
    const int*   econj    = (const int*)d_in[5];
    const int*   ering    = (const int*)d_in[6];
    const int*   est      = (const int*)d_in[7];
    const float* eref     = (const float*)d_in[8];
    const float* t_emb    = (const float*)d_in[9];
    const float* type_emb = (const float*)d_in[10];
    const float* bt_emb   = (const float*)d_in[11];
    const float* conj_emb = (const float*)d_in[12];
    const float* ring_emb = (const float*)d_in[13];
    const float* st_emb   = (const float*)d_in[14];
    const float* refW     = (const float*)d_in[15];
    const float* refb     = (const float*)d_in[16];
    const float* W1       = (const float*)d_in[17];
    const float* b1       = (const float*)d_in[18];
    const float* W2       = (const float*)d_in[19];
    const float* b2       = (const float*)d_in[20];
    const float* Wvs      = (const float*)d_in[21];
    const float* Wls      = (const float*)d_in[22];
    const float* Wsv      = (const float*)d_in[23];
    const float* Wlv      = (const float*)d_in[24];
    const float* Wvl      = (const float*)d_in[25];
    const float* Wsl      = (const float*)d_in[26];
    const float* P0       = (const float*)d_in[27];
    const float* P1o      = (const float*)d_in[28];
    const float* P1e      = (const float*)d_in[29];
    const float* P2       = (const float*)d_in[30];
    const float* filmW    = (const float*)d_in[31];
    const float* filmb    = (const float*)d_in[32];

    float* out = (float*)d_out;

    // ---------------- workspace layout ----------------
    // Int arrays contiguous so one memset covers cnt+cur exactly.
    char* base = (char*)d_ws;
    size_t off = 0;
    auto alloc = [&](size_t bytes, size_t align) -> char* {
        off = (off + align - 1) / align * align;
        char* p = base + off;
        off += bytes;
        return p;
    };
    int* cnt = (int*)alloc((size_t)(2 * N_NODES + N_NODES + 1 + N_EDGES) * sizeof(int), 256);
    int* cur    = cnt + N_NODES;
    int* offs   = cur + N_NODES;
    int* sorted = offs + N_NODES + 1;
    float* hproj = (float*)alloc((size_t)N_NODES * 48 * sizeof(float), 256);
    __hip_bfloat16* Wb1t = (__hip_bfloat16*)alloc(128 * 256 * 2, 256);
    __hip_bfloat16* Wb2t = (__hip_bfloat16*)alloc(432 * 128 * 2, 256);
    off = (off + 255) / 256 * 256;
    __hip_bfloat16* w_buf = (__hip_bfloat16*)(base + off);
    size_t rem = (ws_size > off) ? (ws_size - off) : 0;

    // w_buf capacity (edges) and chunking
    long cap_edges = (long)(rem / (432 * 2));
    int EBLK = (int)(cap_edges / 64);                 // blocks per mlp_chunk launch
    if (EBLK > (N_EDGES + 63) / 64) EBLK = (N_EDGES + 63) / 64;
    if (EBLK < 1) EBLK = 1;
    int NCH, nchunks;
    if ((long)EBLK * 64 >= N_EDGES) {
        NCH = N_NODES; nchunks = 1;
    } else {
        NCH = (int)((long)EBLK * 64 / 21);            // mean degree 16, +31% margin (>5 sigma)
        if (NCH < 1) NCH = 1;
        nchunks = (N_NODES + NCH - 1) / NCH;
    }

    hipMemsetAsync(cnt, 0, 2 * N_NODES * sizeof(int), stream);

    convert_weights<<<(432 * 128 + 255) / 256, 256, 0, stream>>>(W1, W2, Wb1t, Wb2t);
    hproj_kernel<<<(N_NODES * 48 + 255) / 256, 256, 0, stream>>>(h, Wsv, Wsl, hproj);
    hist_kernel<<<(N_EDGES + 255) / 256, 256, 0, stream>>>(eidx, cnt);
    scan_kernel<<<1, 1024, 0, stream>>>(cnt, offs);
    scatter_sort_kernel<<<(N_EDGES + 255) / 256, 256, 0, stream>>>(eidx, offs, cur, sorted);

    for (int k = 0; k < nchunks; k++) {
        const int n_lo = k * NCH;
        int n_hi = n_lo + NCH;
        if (n_hi > N_NODES) n_hi = N_NODES;

        mlp_chunk<<<EBLK, 256, 0, stream>>>(
            h, coords, eidx, sorted, offs, n_lo, n_hi,
            etype, ebt, econj, ering, est, eref, t_emb,
            type_emb, bt_emb, conj_emb, ring_emb, st_emb, refW, refb,
            Wb1t, b1, Wb2t, b2, w_buf);

        const int nb = (n_hi - n_lo + 3) / 4;
        gather_chunk<<<nb, 256, 0, stream>>>(
            h, coords, eidx, sorted, offs, n_lo, n_hi, w_buf, hproj, t_emb,
            Wvs, Wls, Wlv, Wvl, P0, P1o, P1e, P2, filmW, filmb, out);
    }
}

// Round 8
// 1369.862 us; speedup vs baseline: 4.1302x; 1.3758x over previous
//
#include <hip/hip_runtime.h>
#include <hip/hip_bf16.h>

#define N_NODES 25000
#define N_EDGES 400000
#define S 64
#define V 32
#define L2C 16
#define TDIM 64
#define D 336          // S + 6V + 5*L2
#define FILMD 208

#define ES_STR 264     // es row stride in bf16
#define HID_STR 136    // hid row stride in bf16

typedef short bf8 __attribute__((ext_vector_type(8)));
typedef float f4  __attribute__((ext_vector_type(4)));

__device__ __forceinline__ float silu_f(float x) { return x / (1.0f + __expf(-x)); }

__device__ __forceinline__ float rl_f(float v, int lane) {
    return __int_as_float(__builtin_amdgcn_readlane(__float_as_int(v), lane));
}
__device__ __forceinline__ int rl_i(int v, int lane) {
    return __builtin_amdgcn_readlane(v, lane);
}

__device__ __forceinline__ float wsum64(float x) {
    #pragma unroll
    for (int m = 32; m > 0; m >>= 1) x += __shfl_xor(x, m, 64);
    return x;
}
__device__ __forceinline__ float wsum32(float x) {
    #pragma unroll
    for (int m = 16; m > 0; m >>= 1) x += __shfl_xor(x, m, 32);
    return x;
}
__device__ __forceinline__ float wsum16(float x) {
    #pragma unroll
    for (int m = 8; m > 0; m >>= 1) x += __shfl_xor(x, m, 16);
    return x;
}

// ---------------- weight conversion (bf16, transposed) ----------------
__global__ __launch_bounds__(256) void convert_weights(
    const float* __restrict__ W1, const float* __restrict__ W2,
    __hip_bfloat16* __restrict__ Wb1t, __hip_bfloat16* __restrict__ Wb2t)
{
    const int i = blockIdx.x * 256 + threadIdx.x;
    if (i < 128 * 256) {
        const int n = i >> 8, k = i & 255;
        const float v = (k < 252) ? W1[k * 128 + n] : 0.0f;
        Wb1t[i] = __float2bfloat16(v);
    }
    if (i < 432 * 128) {
        const int n = i >> 7, k = i & 127;
        Wb2t[i] = __float2bfloat16(W2[k * 432 + n]);
    }
}

// ---------------- per-node projections hproj[n][48] = [h0@Wsv | h0@Wsl] ----------------
__global__ __launch_bounds__(256) void hproj_kernel(
    const float* __restrict__ h, const float* __restrict__ Wsv,
    const float* __restrict__ Wsl, float* __restrict__ hproj)
{
    const int idx = blockIdx.x * 256 + threadIdx.x;
    if (idx >= N_NODES * 48) return;
    const int n = idx / 48, o = idx - n * 48;
    const float* hr = h + (size_t)n * D;
    float a = 0.f;
    if (o < 32) {
        #pragma unroll 4
        for (int j = 0; j < 64; j++) a = fmaf(hr[j], Wsv[j * 32 + o], a);
    } else {
        const int c = o - 32;
        #pragma unroll 4
        for (int j = 0; j < 64; j++) a = fmaf(hr[j], Wsl[j * 16 + c], a);
    }
    hproj[idx] = a;
}

// ---------------- counting sort by dst (CSR build) ----------------
__global__ __launch_bounds__(256) void hist_kernel(const int* __restrict__ eidx, int* __restrict__ cnt) {
    const int e = blockIdx.x * 256 + threadIdx.x;
    if (e < N_EDGES) atomicAdd(&cnt[eidx[N_EDGES + e]], 1);
}

__global__ __launch_bounds__(1024) void scan_kernel(const int* __restrict__ cnt, int* __restrict__ offs) {
    __shared__ int part[1024];
    const int t = threadIdx.x;
    const int base = t * 25;               // 1024*25 = 25600 >= 25000
    int s = 0;
    for (int k = 0; k < 25; k++) {
        const int b = base + k;
        s += (b < N_NODES) ? cnt[b] : 0;
    }
    part[t] = s;
    __syncthreads();
    for (int off = 1; off < 1024; off <<= 1) {
        int v = (t >= off) ? part[t - off] : 0;
        __syncthreads();
        part[t] += v;
        __syncthreads();
    }
    int run = (t > 0) ? part[t - 1] : 0;
    for (int k = 0; k < 25; k++) {
        const int b = base + k;
        if (b < N_NODES) { offs[b] = run; run += cnt[b]; }
    }
    if (t == 1023) offs[N_NODES] = part[1023];
}

__global__ __launch_bounds__(256) void scatter_sort_kernel(
    const int* __restrict__ eidx, const int* __restrict__ offs,
    int* __restrict__ cur, int* __restrict__ sorted,
    int* __restrict__ ssrc, int* __restrict__ sdst)
{
    const int e = blockIdx.x * 256 + threadIdx.x;
    if (e < N_EDGES) {
        const int s = eidx[e];
        const int d = eidx[N_EDGES + e];
        const int p = offs[d] + atomicAdd(&cur[d], 1);
        if (p >= 0 && p < N_EDGES) { sorted[p] = e; ssrc[p] = s; sdst[p] = d; }
    }
}

// ---------------- MLP chunk kernel: 64 sorted edges / block -> w_buf (sorted order) ----------------
__global__ __launch_bounds__(256, 3) void mlp_chunk(
    const float* __restrict__ h, const float* __restrict__ coords,
    const int* __restrict__ sorted, const int* __restrict__ ssrc,
    const int* __restrict__ sdst,
    const int* __restrict__ offs, int n_lo, int n_hi,
    const int* __restrict__ etype, const int* __restrict__ ebt,
    const int* __restrict__ econj, const int* __restrict__ ering,
    const int* __restrict__ est, const float* __restrict__ eref,
    const float* __restrict__ t_emb,
    const float* __restrict__ type_emb, const float* __restrict__ bt_emb,
    const float* __restrict__ conj_emb, const float* __restrict__ ring_emb,
    const float* __restrict__ st_emb,
    const float* __restrict__ refW, const float* __restrict__ refb,
    const __hip_bfloat16* __restrict__ Wb1t, const float* __restrict__ b1,
    const __hip_bfloat16* __restrict__ Wb2t, const float* __restrict__ b2,
    __hip_bfloat16* __restrict__ w_buf)
{
    __shared__ __hip_bfloat16 esA[64 * ES_STR];   // 33792 B
    __shared__ __hip_bfloat16 hidA[64 * HID_STR]; // 17408 B   -> 51200 B, 3 blocks/CU

    const int wid = threadIdx.x >> 6;
    const int l   = threadIdx.x & 63;
    const int pbase = offs[n_lo];
    const int pend  = offs[n_hi];
    const int start = pbase + blockIdx.x * 64;
    if (start >= pend) return;

    // ---------------- Stage 1: edge features -> es (bf16) ----------------
    // Lane l preloads ALL per-edge scalars for block edge l (coalesced / batched
    // gathers) -> in-loop access is pure readlane, no serial load chains.
    {
        const int myp = min(start + l, pend - 1);
        const int e_l   = sorted[myp];
        const int src_l = ssrc[myp];
        const int dst_l = sdst[myp];
        const int et_l = etype[e_l];
        const int bt_l = ebt[e_l];
        const int cj_l = econj[e_l];
        const int rg_l = ering[e_l];
        const int st_l = est[e_l];
        const float er_l = eref[e_l];
        const float csx_l = coords[3 * src_l], csy_l = coords[3 * src_l + 1], csz_l = coords[3 * src_l + 2];
        const float cdx_l = coords[3 * dst_l], cdy_l = coords[3 * dst_l + 1], cdz_l = coords[3 * dst_l + 2];

        for (int i = 0; i < 16; i++) {
            const int le = wid * 16 + i;
            const int src = rl_i(src_l, le);
            const int dst = rl_i(dst_l, le);
            const float dx = rl_f(cdx_l, le) - rl_f(csx_l, le);
            const float dy = rl_f(cdy_l, le) - rl_f(csy_l, le);
            const float dz = rl_f(cdz_l, le) - rl_f(csz_l, le);
            const float dist = sqrtf(dx * dx + dy * dy + dz * dz + 1e-12f);
            __hip_bfloat16* es = esA + le * ES_STR;
            es[60 + l]  = __float2bfloat16(h[(size_t)src * D + l]);
            es[124 + l] = __float2bfloat16(h[(size_t)dst * D + l]);
            es[188 + l] = __float2bfloat16(t_emb[(size_t)dst * TDIM + l]);
            const int et = rl_i(et_l, le);
            const int bt = rl_i(bt_l, le);
            const int ci = (bt >= 0) ? rl_i(cj_l, le) : 2;
            const int ri = (bt >= 0) ? rl_i(rg_l, le) : 2;
            const int si = rl_i(st_l, le) + 1;
            const float er = rl_f(er_l, le);
            if (l < 16) {
                const float mu = (float)l * (5.0f / 15.0f);
                const float t = (dist - mu) * 3.0f;
                es[l] = __float2bfloat16(__expf(-t * t));
                es[16 + l] = __float2bfloat16(type_emb[et * 16 + l]);
            }
            if (l < 8) {
                es[32 + l] = __float2bfloat16(bt_emb[(bt + 1) * 8 + l]);
                const float ddv = dist - er;
                const float hr = (er > 0.f) ? 1.f : 0.f;
                es[52 + l] = __float2bfloat16(
                    fabsf(ddv) * refW[l] + ddv * refW[8 + l] + hr * refW[16 + l] + refb[l]);
            }
            if (l < 4) {
                es[40 + l] = __float2bfloat16(conj_emb[ci * 4 + l]);
                es[44 + l] = __float2bfloat16(ring_emb[ri * 4 + l]);
                es[48 + l] = __float2bfloat16(st_emb[si * 4 + l]);
                es[252 + l] = __float2bfloat16(0.0f);  // K padding
            }
        }
    }
    __syncthreads();

    // ---------------- Stage 2: GEMM1  hid[64x128] = silu(es @ W1 + b1) ----------------
    {
        const int q = l >> 4;
        const int t16 = l & 15;
        f4 acc[4][2];
        #pragma unroll
        for (int mt = 0; mt < 4; mt++)
            #pragma unroll
            for (int nt = 0; nt < 2; nt++) acc[mt][nt] = (f4){0.f, 0.f, 0.f, 0.f};
        const int n0 = wid * 32 + t16;
        #pragma unroll
        for (int kk = 0; kk < 256; kk += 32) {
            const int k0 = kk + q * 8;
            bf8 a[4];
            #pragma unroll
            for (int mt = 0; mt < 4; mt++)
                a[mt] = *(const bf8*)(esA + (mt * 16 + t16) * ES_STR + k0);
            bf8 b[2];
            b[0] = *(const bf8*)(Wb1t + (size_t)n0 * 256 + k0);
            b[1] = *(const bf8*)(Wb1t + (size_t)(n0 + 16) * 256 + k0);
            #pragma unroll
            for (int mt = 0; mt < 4; mt++) {
                acc[mt][0] = __builtin_amdgcn_mfma_f32_16x16x32_bf16(a[mt], b[0], acc[mt][0], 0, 0, 0);
                acc[mt][1] = __builtin_amdgcn_mfma_f32_16x16x32_bf16(a[mt], b[1], acc[mt][1], 0, 0, 0);
            }
        }
        const float bias0 = b1[n0], bias1 = b1[n0 + 16];
        #pragma unroll
        for (int mt = 0; mt < 4; mt++) {
            #pragma unroll
            for (int r = 0; r < 4; r++) {
                const int m = mt * 16 + q * 4 + r;
                hidA[m * HID_STR + n0]      = __float2bfloat16(silu_f(acc[mt][0][r] + bias0));
                hidA[m * HID_STR + n0 + 16] = __float2bfloat16(silu_f(acc[mt][1][r] + bias1));
            }
        }
    }
    __syncthreads();

    // ---------------- Stage 3: GEMM2 -> w_buf rows (sorted-position order) ----------------
    {
        const int q = l >> 4;
        const int t16 = l & 15;
        bf8 a2[4][4];
        #pragma unroll
        for (int ks = 0; ks < 4; ks++) {
            const int k0 = ks * 32 + q * 8;
            #pragma unroll
            for (int mt = 0; mt < 4; mt++)
                a2[mt][ks] = *(const bf8*)(hidA + (mt * 16 + t16) * HID_STR + k0);
        }
        const size_t wb = (size_t)(start - pbase);
        for (int t = wid; t < 27; t += 4) {
            const int n = t * 16 + t16;
            f4 acc[4];
            #pragma unroll
            for (int mt = 0; mt < 4; mt++) acc[mt] = (f4){0.f, 0.f, 0.f, 0.f};
            #pragma unroll
            for (int ks = 0; ks < 4; ks++) {
                const bf8 b = *(const bf8*)(Wb2t + (size_t)n * 128 + ks * 32 + q * 8);
                #pragma unroll
                for (int mt = 0; mt < 4; mt++)
                    acc[mt] = __builtin_amdgcn_mfma_f32_16x16x32_bf16(a2[mt][ks], b, acc[mt], 0, 0, 0);
            }
            const float bias = b2[n];
            #pragma unroll
            for (int mt = 0; mt < 4; mt++) {
                #pragma unroll
                for (int r = 0; r < 4; r++) {
                    const int m = mt * 16 + q * 4 + r;
                    w_buf[(wb + m) * 432 + n] = __float2bfloat16(acc[mt][r] + bias);
                }
            }
        }
    }
}

// ---------------- Gather chunk kernel: one wave per dst node, fused node epilogue ----------------
// Round-8: hoisted Wvs/Wls/Wlv-Wvl into registers (removes ~48 global loads per
// edge per lane from the FMA chains); batch-preloaded sorted srcs+coords via
// readlane (removes the serial sorted->eidx->coords chain).
__global__ __launch_bounds__(256, 2) void gather_chunk(
    const float* __restrict__ h, const float* __restrict__ coords,
    const int* __restrict__ ssrc,
    const int* __restrict__ offs, int n_lo, int n_hi,
    const __hip_bfloat16* __restrict__ w_buf,
    const float* __restrict__ hproj, const float* __restrict__ t_emb,
    const float* __restrict__ Wvs, const float* __restrict__ Wls,
    const float* __restrict__ Wlv, const float* __restrict__ Wvl,
    const float* __restrict__ P0, const float* __restrict__ P1o,
    const float* __restrict__ P1e, const float* __restrict__ P2,
    const float* __restrict__ filmW, const float* __restrict__ filmb,
    float* __restrict__ out)
{
    __shared__ float sc[4][256];    // dv32 | ql16 | eci48 | t112 160
    __shared__ float agL[4][344];
    __shared__ float tvL[4][64];

    const int wid = threadIdx.x >> 6;
    const int l   = threadIdx.x & 63;
    const int n   = n_lo + blockIdx.x * 4 + wid;
    if (n >= n_hi) return;

    float* dv   = sc[wid];
    float* ql   = dv + 32;
    float* eci  = ql + 16;
    float* t112 = eci + 48;
    float* ag   = agL[wid];
    float* tv   = tvL[wid];

    const float R2 = 0.7071067811865476f;
    const float R6 = 0.4082482904638631f;

    const float cdx = coords[3 * n], cdy = coords[3 * n + 1], cdz = coords[3 * n + 2];
    const int pbase = offs[n_lo];
    const int pbeg = offs[n], pend = offs[n + 1];
    const int vv = l & 31, cc = l & 15;
    const bool loV = (l < 32);
    const bool hiA = (l >= 32) && !(l & 16);   // lanes 32..47
    const int v0 = (l & 16) ? 16 : 0;          // m2 v-half for lanes 32..63

    // ---- hoisted small weights (loop-invariant, ~64 VGPRs) ----
    float Wvs_r[32];
    #pragma unroll
    for (int v = 0; v < 32; v++) Wvs_r[v] = Wvs[v * 64 + l];
    float Wls_r[16];
    #pragma unroll
    for (int c = 0; c < 16; c++) Wls_r[c] = Wls[c * 64 + l];
    float WX_r[16];     // lanes<32: Wlv[c][vv];  lanes>=32: Wvl[v0+k][cc]
    #pragma unroll
    for (int k = 0; k < 16; k++)
        WX_r[k] = loV ? Wlv[k * 32 + vv] : Wvl[(v0 + k) * 16 + cc];

    float am0 = 0.f;
    float am1[6] = {0.f, 0.f, 0.f, 0.f, 0.f, 0.f};
    float am2[5] = {0.f, 0.f, 0.f, 0.f, 0.f};

    for (int pb = pbeg; pb < pend; pb += 64) {
        const int tail = pend - pb;
        const int bcnt = tail < 64 ? tail : 64;
        const int bpos = pb + (l < tail ? l : tail - 1);
        const int bsrc_l = ssrc[bpos];
        const float bcsx = coords[3 * bsrc_l];
        const float bcsy = coords[3 * bsrc_l + 1];
        const float bcsz = coords[3 * bsrc_l + 2];

        for (int i = 0; i < bcnt; i++) {
            const int src = rl_i(bsrc_l, i);
            const int p = pb + i;

            // ---- issue all loads for this edge up front ----
            const float* hr = h + (size_t)src * D;
            const __hip_bfloat16* wr = w_buf + (size_t)(p - pbase) * 432;
            const float h0 = hr[l];
            const float w0 = __bfloat162float(wr[l]);
            const float w1 = __bfloat162float(wr[64 + l]);
            const float w2 = __bfloat162float(wr[128 + l]);
            float a0, a1, a2, b0, b1, b2, pxv, w3, w4, w5, w6, w7, w8;
            float c0, c1, c2, c3, c4, pxl, w9, w10, w11;
            if (loV) {
                a0 = hr[64 + 3 * vv];  a1 = hr[65 + 3 * vv];  a2 = hr[66 + 3 * vv];
                b0 = hr[160 + 3 * vv]; b1 = hr[161 + 3 * vv]; b2 = hr[162 + 3 * vv];
                pxv = hproj[(size_t)src * 48 + vv];
                w3 = __bfloat162float(wr[192 + vv]);
                w4 = __bfloat162float(wr[224 + vv]);
                w5 = __bfloat162float(wr[256 + vv]);
                w6 = __bfloat162float(wr[288 + vv]);
                w7 = __bfloat162float(wr[320 + vv]);
                w8 = __bfloat162float(wr[352 + vv]);
                c0 = c1 = c2 = c3 = c4 = pxl = w9 = w10 = w11 = 0.f;
            } else {
                c0 = hr[256 + 5 * cc]; c1 = hr[257 + 5 * cc]; c2 = hr[258 + 5 * cc];
                c3 = hr[259 + 5 * cc]; c4 = hr[260 + 5 * cc];
                pxl = hproj[(size_t)src * 48 + 32 + cc];
                w9  = __bfloat162float(wr[384 + cc]);
                w10 = __bfloat162float(wr[400 + cc]);
                w11 = __bfloat162float(wr[416 + cc]);
                a0 = a1 = a2 = b0 = b1 = b2 = pxv = w3 = w4 = w5 = w6 = w7 = w8 = 0.f;
            }

            // ---- geometry (src coords from batch registers, no load) ----
            const float dx = cdx - rl_f(bcsx, i);
            const float dy = cdy - rl_f(bcsy, i);
            const float dz = cdz - rl_f(bcsz, i);
            const float dist = sqrtf(dx * dx + dy * dy + dz * dz + 1e-12f);
            const float inv = 1.0f / dist;
            const float ux = dx * inv, uy = dy * inv, uz = dz * inv;
            float y2a[5];
            y2a[0] = 2.f * R2 * ux * uy;
            y2a[1] = 2.f * R2 * ux * uz;
            y2a[2] = 2.f * R2 * uy * uz;
            y2a[3] = R2 * (ux * ux - uy * uy);
            y2a[4] = R6 * (ux * ux + uy * uy - 2.f * uz * uz);

            if (loV) {
                dv[l] = a0 * ux + a1 * uy + a2 * uz;
                t112[l * 5 + 0] = R2 * (a0 * uy + a1 * ux);
                t112[l * 5 + 1] = R2 * (a0 * uz + a2 * ux);
                t112[l * 5 + 2] = R2 * (a1 * uz + a2 * uy);
                t112[l * 5 + 3] = R2 * (a0 * ux - a1 * uy);
                t112[l * 5 + 4] = R6 * (a0 * ux + a1 * uy - 2.f * a2 * uz);
            } else if (hiA) {
                ql[cc] = c0 * y2a[0] + c1 * y2a[1] + c2 * y2a[2] + c3 * y2a[3] + c4 * y2a[4];
                eci[cc * 3 + 0] = R2 * (c0 * uy + c1 * uz + c3 * ux) + R6 * c4 * ux;
                eci[cc * 3 + 1] = R2 * (c0 * ux + c2 * uz - c3 * uy) + R6 * c4 * uy;
                eci[cc * 3 + 2] = R2 * (c1 * ux + c2 * uy) - 2.f * R6 * c4 * uz;
            }

            // m0 (all lanes, channel l)
            {
                float t1 = 0.f, t2 = 0.f;
                #pragma unroll
                for (int v = 0; v < 32; v++) t1 = fmaf(dv[v], Wvs_r[v], t1);
                #pragma unroll
                for (int c = 0; c < 16; c++) t2 = fmaf(ql[c], Wls_r[c], t2);
                am0 += w0 * h0 + w1 * t1 + w2 * t2;
            }

            if (loV) {
                // m1o / m1e (lanes 0..31, v = l)
                const float co0 = b1 * uz - b2 * uy;
                const float co1 = b2 * ux - b0 * uz;
                const float co2 = b0 * uy - b1 * ux;
                const float ce0 = a1 * uz - a2 * uy;
                const float ce1 = a2 * ux - a0 * uz;
                const float ce2 = a0 * uy - a1 * ux;
                float t0 = 0.f, t1 = 0.f, t2 = 0.f;
                #pragma unroll
                for (int c = 0; c < 16; c++) {
                    const float wl = WX_r[c];
                    t0 = fmaf(eci[c * 3 + 0], wl, t0);
                    t1 = fmaf(eci[c * 3 + 1], wl, t1);
                    t2 = fmaf(eci[c * 3 + 2], wl, t2);
                }
                am1[0] += w3 * a0 + w4 * pxv * ux + w5 * co0 + w6 * t0;
                am1[1] += w3 * a1 + w4 * pxv * uy + w5 * co1 + w6 * t1;
                am1[2] += w3 * a2 + w4 * pxv * uz + w5 * co2 + w6 * t2;
                am1[3] += w7 * b0 + w8 * ce0;
                am1[4] += w7 * b1 + w8 * ce1;
                am1[5] += w7 * b2 + w8 * ce2;
            } else {
                // m2 (lanes 32..63, channel cc, v-half v0..v0+15)
                float tl0 = 0, tl1 = 0, tl2 = 0, tl3 = 0, tl4 = 0;
                #pragma unroll
                for (int vk = 0; vk < 16; vk++) {
                    const int v = v0 + vk;
                    const float wv = WX_r[vk];
                    tl0 = fmaf(t112[v * 5 + 0], wv, tl0);
                    tl1 = fmaf(t112[v * 5 + 1], wv, tl1);
                    tl2 = fmaf(t112[v * 5 + 2], wv, tl2);
                    tl3 = fmaf(t112[v * 5 + 3], wv, tl3);
                    tl4 = fmaf(t112[v * 5 + 4], wv, tl4);
                }
                am2[0] += w10 * tl0;
                am2[1] += w10 * tl1;
                am2[2] += w10 * tl2;
                am2[3] += w10 * tl3;
                am2[4] += w10 * tl4;
                if (hiA) {   // add the non-split terms exactly once
                    am2[0] += w9 * c0 + w11 * pxl * y2a[0];
                    am2[1] += w9 * c1 + w11 * pxl * y2a[1];
                    am2[2] += w9 * c2 + w11 * pxl * y2a[2];
                    am2[3] += w9 * c3 + w11 * pxl * y2a[3];
                    am2[4] += w9 * c4 + w11 * pxl * y2a[4];
                }
            }
        }
    }

    // combine m2 v-halves (lane 32+c gets lane 48+c's partial and vice versa)
    #pragma unroll
    for (int k = 0; k < 5; k++) am2[k] += __shfl_xor(am2[k], 16, 64);

    // ---------------- stash accumulated messages to LDS (wave-synchronous) ----------------
    ag[l] = am0;
    if (loV) {
        ag[64 + 3 * l + 0] = am1[0];
        ag[64 + 3 * l + 1] = am1[1];
        ag[64 + 3 * l + 2] = am1[2];
        ag[160 + 3 * l + 0] = am1[3];
        ag[160 + 3 * l + 1] = am1[4];
        ag[160 + 3 * l + 2] = am1[5];
    }
    if (hiA) {
        #pragma unroll
        for (int k = 0; k < 5; k++) ag[256 + 5 * cc + k] = am2[k];
    }
    tv[l] = t_emb[(size_t)n * TDIM + l];

    const float* hrow = h + (size_t)n * D;

    const int c2 = 128 + l;
    const int c3 = 192 + (l & 15);
    float f0 = filmb[l], f1 = filmb[64 + l], f2 = filmb[c2], f3 = filmb[c3];
    #pragma unroll 4
    for (int t = 0; t < 64; t++) {
        const float tt = tv[t];
        const float* fr = filmW + t * FILMD;
        f0 = fmaf(tt, fr[l], f0);
        f1 = fmaf(tt, fr[64 + l], f1);
        f2 = fmaf(tt, fr[c2], f2);
        f3 = fmaf(tt, fr[c3], f3);
    }

    {
        float a0 = 0.f;
        #pragma unroll 4
        for (int j = 0; j < 64; j++) a0 = fmaf(ag[j], P0[j * 64 + l], a0);
        a0 = silu_f(a0);
        const float hn0 = hrow[l] + a0;
        const float mu = wsum64(hn0) * (1.0f / 64.0f);
        const float d0 = hn0 - mu;
        const float var = wsum64(d0 * d0) * (1.0f / 64.0f);
        out[(size_t)n * D + l] = d0 * rsqrtf(var + 1e-6f) * (1.f + f0) + f1;
    }

    {
        const int v = l & 31;
        const bool iso = (l < 32);
        const float* Pm = iso ? P1o : P1e;
        const int base = iso ? 64 : 160;
        float a0 = 0.f, a1 = 0.f, a2 = 0.f;
        #pragma unroll 4
        for (int u = 0; u < 32; u++) {
            const float p = Pm[u * 32 + v];
            a0 = fmaf(ag[base + 3 * u + 0], p, a0);
            a1 = fmaf(ag[base + 3 * u + 1], p, a1);
            a2 = fmaf(ag[base + 3 * u + 2], p, a2);
        }
        const float x0 = hrow[base + 3 * v + 0] + a0;
        const float x1 = hrow[base + 3 * v + 1] + a1;
        const float x2 = hrow[base + 3 * v + 2] + a2;
        const float ssq = x0 * x0 + x1 * x1 + x2 * x2;
        const float s = wsum32(ssq);
        const float rinv = rsqrtf(s * (1.f / 32.f) + 1e-6f);
        const float scv = (1.f + f2) * rinv;
        out[(size_t)n * D + base + 3 * v + 0] = x0 * scv;
        out[(size_t)n * D + base + 3 * v + 1] = x1 * scv;
        out[(size_t)n * D + base + 3 * v + 2] = x2 * scv;
    }

    {
        const int c = l & 15;
        float xk[5];
        float ssq = 0.f;
        #pragma unroll
        for (int k = 0; k < 5; k++) {
            float a = 0.f;
            #pragma unroll
            for (int u = 0; u < 16; u++) a = fmaf(ag[256 + 5 * u + k], P2[u * 16 + c], a);
            const float x = hrow[256 + 5 * c + k] + a;
            xk[k] = x;
            ssq += x * x;
        }
        const float s = wsum16(ssq);
        const float rinv = rsqrtf(s * (1.f / 16.f) + 1e-6f);
        const float scv = (1.f + f3) * rinv;
        if (l < 16) {
            #pragma unroll
            for (int k = 0; k < 5; k++) out[(size_t)n * D + 256 + 5 * c + k] = xk[k] * scv;
        }
    }
}

extern "C" void kernel_launch(void* const* d_in, const int* in_sizes, int n_in,
                              void* d_out, int out_size, void* d_ws, size_t ws_size,
                              hipStream_t stream)
{
    const float* h        = (const float*)d_in[0];
    const float* coords   = (const float*)d_in[1];
    const int*   eidx     = (const int*)d_in[2];
    const int*   etype    = (const int*)d_in[3];
    const int*   ebt      = (const int*)d_in[4];
    const int*   econj    = (const int*)d_in[5];
    const int*   ering    = (const int*)d_in[6];
    const int*   est      = (const int*)d_in[7];
    const float* eref     = (const float*)d_in[8];
    const float* t_emb    = (const float*)d_in[9];
    const float* type_emb = (const float*)d_in[10];
    const float* bt_emb   = (const float*)d_in[11];
    const float* conj_emb = (const float*)d_in[12];
    const float* ring_emb = (const float*)d_in[13];
    const float* st_emb   = (const float*)d_in[14];
    const float* refW     = (const float*)d_in[15];
    const float* refb     = (const float*)d_in[16];
    const float* W1       = (const float*)d_in[17];
    const float* b1       = (const float*)d_in[18];
    const float* W2       = (const float*)d_in[19];
    const float* b2       = (const float*)d_in[20];
    const float* Wvs      = (const float*)d_in[21];
    const float* Wls      = (const float*)d_in[22];
    const float* Wsv      = (const float*)d_in[23];
    const float* Wlv      = (const float*)d_in[24];
    const float* Wvl      = (const float*)d_in[25];
    const float* Wsl      = (const float*)d_in[26];
    const float* P0       = (const float*)d_in[27];
    const float* P1o      = (const float*)d_in[28];
    const float* P1e      = (const float*)d_in[29];
    const float* P2       = (const float*)d_in[30];
    const float* filmW    = (const float*)d_in[31];
    const float* filmb    = (const float*)d_in[32];

    float* out = (float*)d_out;

    // ---------------- workspace layout ----------------
    // Int arrays contiguous so one memset covers cnt+cur exactly.
    char* base = (char*)d_ws;
    size_t off = 0;
    auto alloc = [&](size_t bytes, size_t align) -> char* {
        off = (off + align - 1) / align * align;
        char* p = base + off;
        off += bytes;
        return p;
    };
    int* cnt = (int*)alloc((size_t)(2 * N_NODES + N_NODES + 1 + 3 * N_EDGES) * sizeof(int), 256);
    int* cur    = cnt + N_NODES;
    int* offs   = cur + N_NODES;
    int* sorted = offs + N_NODES + 1;
    int* ssrc   = sorted + N_EDGES;
    int* sdst   = ssrc + N_EDGES;
    float* hproj = (float*)alloc((size_t)N_NODES * 48 * sizeof(float), 256);
    __hip_bfloat16* Wb1t = (__hip_bfloat16*)alloc(128 * 256 * 2, 256);
    __hip_bfloat16* Wb2t = (__hip_bfloat16*)alloc(432 * 128 * 2, 256);
    off = (off + 255) / 256 * 256;
    __hip_bfloat16* w_buf = (__hip_bfloat16*)(base + off);
    size_t rem = (ws_size > off) ? (ws_size - off) : 0;

    // w_buf capacity (edges) and chunking
    long cap_edges = (long)(rem / (432 * 2));
    int EBLK = (int)(cap_edges / 64);                 // blocks per mlp_chunk launch
    if (EBLK > (N_EDGES + 63) / 64) EBLK = (N_EDGES + 63) / 64;
    if (EBLK < 1) EBLK = 1;
    int NCH, nchunks;
    if ((long)EBLK * 64 >= N_EDGES) {
        NCH = N_NODES; nchunks = 1;
    } else {
        NCH = (int)((long)EBLK * 64 / 21);            // mean degree 16, +31% margin (>5 sigma)
        if (NCH < 1) NCH = 1;
        nchunks = (N_NODES + NCH - 1) / NCH;
    }

    hipMemsetAsync(cnt, 0, 2 * N_NODES * sizeof(int), stream);

    convert_weights<<<(432 * 128 + 255) / 256, 256, 0, stream>>>(W1, W2, Wb1t, Wb2t);
    hproj_kernel<<<(N_NODES * 48 + 255) / 256, 256, 0, stream>>>(h, Wsv, Wsl, hproj);
    hist_kernel<<<(N_EDGES + 255) / 256, 256, 0, stream>>>(eidx, cnt);
    scan_kernel<<<1, 1024, 0, stream>>>(cnt, offs);
    scatter_sort_kernel<<<(N_EDGES + 255) / 256, 256, 0, stream>>>(eidx, offs, cur, sorted, ssrc, sdst);

    for (int k = 0; k < nchunks; k++) {
        const int n_lo = k * NCH;
        int n_hi = n_lo + NCH;
        if (n_hi > N_NODES) n_hi = N_NODES;

        mlp_chunk<<<EBLK, 256, 0, stream>>>(
            h, coords, sorted, ssrc, sdst, offs, n_lo, n_hi,
            etype, ebt, econj, ering, est, eref, t_emb,
            type_emb, bt_emb, conj_emb, ring_emb, st_emb, refW, refb,
            Wb1t, b1, Wb2t, b2, w_buf);

        const int nb = (n_hi - n_lo + 3) / 4;
        gather_chunk<<<nb, 256, 0, stream>>>(
            h, coords, ssrc, offs, n_lo, n_hi, w_buf, hproj, t_emb,
            Wvs, Wls, Wlv, Wvl, P0, P1o, P1e, P2, filmW, filmb, out);
    }
}